// Round 12
// baseline (107.631 us; speedup 1.0000x reference)
//
#include <hip/hip_runtime.h>
#include <hip/hip_bf16.h>

typedef short bf16x8 __attribute__((ext_vector_type(8)));
typedef float f32x4  __attribute__((ext_vector_type(4)));
typedef int   i32x4  __attribute__((ext_vector_type(4)));

#define T_AUDIO 262144
#define PADL 384
#define CUTOFF 513
#define CPAD 576       // layout: p=c for c<=256, hole 257..263, p=c+7 for c>=257, tail 520..575 zero
#define NMELS 80
#define SEGLEN2 66304  // 255*256 + 1024 samples per 256-frame tile
#define EB2 66304      // bytes per parity plane in LDS (33152 bf16)

__device__ __forceinline__ unsigned short f2bf(float f){
  union { float f; unsigned u; } v; v.f = f;
  return (unsigned short)((v.u + 0x7FFFu + ((v.u >> 16) & 1u)) >> 16);
}

__device__ __forceinline__ void gload_lds16(const void* g, void* l){
  __builtin_amdgcn_global_load_lds(
      (const __attribute__((address_space(1))) unsigned int*)g,
      (__attribute__((address_space(3))) unsigned int*)l, 16, 0, 0);
}

// ---------- k_extra: bin-256 column (f32 dot) + zero pad cols (hole 257..263, tail 520..575) ----------
__global__ void k_extra(const float* __restrict__ audio,
                        const float* __restrict__ basis,
                        unsigned short* __restrict__ magT){
  __shared__ float swr[4], swi[4];
  int tid = threadIdx.x;
  int gid = blockIdx.x * 256 + tid;
  int b   = gid >> 17;
  int rem = gid & 131071;
  int t   = rem >> 7;
  int k0  = (rem & 127) << 3;
  int s0  = t * 256 + k0 - PADL;
  const float* ap = audio + (long)b * T_AUDIO;
  float v[8];
  if (s0 >= 0 && s0 + 7 < T_AUDIO){
    f32x4 a0 = *(const f32x4*)(ap + s0);
    f32x4 a1 = *(const f32x4*)(ap + s0 + 4);
    v[0]=a0[0]; v[1]=a0[1]; v[2]=a0[2]; v[3]=a0[3];
    v[4]=a1[0]; v[5]=a1[1]; v[6]=a1[2]; v[7]=a1[3];
  } else {
    #pragma unroll
    for (int e = 0; e < 8; ++e){
      int s = s0 + e;
      if (s < 0) s = -s;
      if (s >= T_AUDIO) s = 2*(T_AUDIO-1) - s;
      v[e] = ap[s];
    }
  }
  const float* r256 = basis + 256 * 1024 + k0;
  const float* i256 = basis + 769 * 1024 + k0;
  float dr = 0.f, di = 0.f;
  #pragma unroll
  for (int e = 0; e < 8; ++e){ dr += v[e]*r256[e]; di += v[e]*i256[e]; }
  #pragma unroll
  for (int off = 32; off; off >>= 1){
    dr += __shfl_down(dr, off, 64);
    di += __shfl_down(di, off, 64);
  }
  int lane = tid & 63, wid = tid >> 6;
  if (lane == 0){ swr[wid] = dr; swi[wid] = di; }
  __syncthreads();
  long tg = (long)b * 1024 + t;
  if (tid == 0 || tid == 128){
    float R = (tid == 0) ? (swr[0] + swr[1]) : (swr[2] + swr[3]);
    float I = (tid == 0) ? (swi[0] + swi[1]) : (swi[2] + swi[3]);
    magT[tg * CPAD + 256] = f2bf(sqrtf(R*R + I*I));
  }
  int c = tid & 127;
  if (c < 63){
    int p = (c < 7) ? (257 + c) : (513 + c);   // 257..263 and 520..575
    magT[tg * CPAD + p] = 0;
  }
}

// ---------- k_basis4: frag-major A  bi2f[(((g*2+p)*16+s)*8+f)*64+l] 16B chunks ----------
__global__ void k_basis4(const float* __restrict__ basis, unsigned short* __restrict__ bi2f){
  int CI = blockIdx.x * 256 + threadIdx.x;     // 65536 chunks
  int l  = CI & 63;
  int f  = (CI >> 6) & 7;
  int s  = (CI >> 9) & 15;
  int p  = (CI >> 13) & 1;
  int g  = CI >> 14;
  int R  = g * 128 + (f >> 2) * 64 + (f & 3) * 16 + (l & 15);
  int srcr = (R >> 1) + 513 * (R & 1);
  const float* sp = basis + srcr * 1024 + 2 * (s * 32 + (l >> 4) * 8) + p;
  bf16x8 o;
  #pragma unroll
  for (int e = 0; e < 8; ++e) o[e] = (short)f2bf(sp[2*e]);
  *(bf16x8*)(bi2f + (long)CI * 8) = o;
}

// ---------- k_w: mel weights [80][576] bf16, mirror-shifted (+7) layout ----------
__global__ void k_w(const float* __restrict__ w, unsigned short* __restrict__ wb){
  int gid = blockIdx.x * 256 + threadIdx.x;
  if (gid >= NMELS * CPAD) return;
  int m = gid / CPAD, p = gid % CPAD;
  float v = 0.f;
  if (p <= 256) v = w[m * CUTOFF + p];
  else if (p >= 264 && p <= 519) v = w[m * CUTOFF + (p - 7)];
  wb[gid] = f2bf(v);
}

// ---------- k_stft: 128 x 256 tile, 4 waves @ 1/SIMD (512-VGPR budget), barrier-free K-loop ----------
__launch_bounds__(256, 1)
__global__ void k_stft(const unsigned short* __restrict__ bi2f,
                       const float* __restrict__ audio,
                       unsigned short* __restrict__ magT){
  __shared__ __align__(16) char LDS[2 * EB2];   // evens | odds ; reused for transpose
  const int tid = threadIdx.x;
  const int l   = tid & 63, w = tid >> 6;
  const int wm  = w >> 1, wn = w & 1;
  const int x   = l & 15, h = l >> 4;

  int bx = blockIdx.x;
  int sw = ((bx & 7) << 6) | (bx >> 3);   // XCD swizzle (512 % 8 == 0, bijective)
  const int g   = sw & 3;
  const int nt2 = sw >> 2;                // 0..127 : frames [nt2*256, +256)

  // ---- stage audio segment once: evens/odds bf16, chunk XOR swizzle ----
  {
    const long segbase = (long)(nt2 >> 2) * T_AUDIO;
    const int  sstart  = ((nt2 & 3) << 16) - PADL;     // (nt2&3)*256*256 - 384
    const float* ap = audio + segbase;
    #pragma unroll 4
    for (int it = 0; it < 33; ++it){
      int p0 = (it * 256 + tid) * 8;
      if (p0 < SEGLEN2){
        int sg = sstart + p0;
        float v[8];
        if (sg >= 0 && sg + 7 < T_AUDIO){
          f32x4 a0 = *(const f32x4*)(ap + sg);
          f32x4 a1 = *(const f32x4*)(ap + sg + 4);
          v[0]=a0[0]; v[1]=a0[1]; v[2]=a0[2]; v[3]=a0[3];
          v[4]=a1[0]; v[5]=a1[1]; v[6]=a1[2]; v[7]=a1[3];
        } else {
          #pragma unroll
          for (int e = 0; e < 8; ++e){
            int ss = sg + e;
            if (ss < 0) ss = -ss;
            if (ss >= T_AUDIO) ss = 2*(T_AUDIO-1) - ss;
            v[e] = ap[ss];
          }
        }
        unsigned long long pe = (unsigned long long)f2bf(v[0])
                              | ((unsigned long long)f2bf(v[2]) << 16)
                              | ((unsigned long long)f2bf(v[4]) << 32)
                              | ((unsigned long long)f2bf(v[6]) << 48);
        unsigned long long po = (unsigned long long)f2bf(v[1])
                              | ((unsigned long long)f2bf(v[3]) << 16)
                              | ((unsigned long long)f2bf(v[5]) << 32)
                              | ((unsigned long long)f2bf(v[7]) << 48);
        int ep = p0 >> 1;
        int C  = ep >> 3;
        int ad = ((C ^ ((C >> 4) & 15)) << 4) + ((ep & 4) << 1);
        *(unsigned long long*)(LDS + ad)       = pe;
        *(unsigned long long*)(LDS + EB2 + ad) = po;
      }
    }
  }
  __syncthreads();

  // ---- A frag-major bases (L2-resident); same bi2f layout as before ----
  const char* AgE = (const char*)bi2f + (long)(g * 256 + wm * 4) * 1024 + l * 16;
  const char* AgO = AgE + 131072;

  int C0[8];
  #pragma unroll
  for (int j = 0; j < 8; ++j) C0[j] = (wn * 128 + j * 16 + x) * 16 + h;

  f32x4 accE[4][8] = {}, accO[4][8] = {};
  bf16x8 aE[2][4], aO[2][4];
  #pragma unroll
  for (int i = 0; i < 4; ++i){
    aE[0][i] = *(const bf16x8*)(AgE + i * 1024);
    aO[0][i] = *(const bf16x8*)(AgO + i * 1024);
  }

  #pragma unroll
  for (int s = 0; s < 16; ++s){
    const int cur = s & 1, nxt = cur ^ 1;
    if (s < 15){
      #pragma unroll
      for (int i = 0; i < 4; ++i){
        aE[nxt][i] = *(const bf16x8*)(AgE + (s + 1) * 8192 + i * 1024);
        aO[nxt][i] = *(const bf16x8*)(AgO + (s + 1) * 8192 + i * 1024);
      }
    }
    // E half: read 8 B-frags, MFMA 32 (O reads issued after, hidden under E MFMAs)
    bf16x8 bqE[8];
    #pragma unroll
    for (int j = 0; j < 8; ++j){
      int C  = C0[j] + s * 4;
      int ad = (C ^ ((C >> 4) & 15)) << 4;
      bqE[j] = *(const bf16x8*)(LDS + ad);
    }
    __builtin_amdgcn_s_setprio(1);
    #pragma unroll
    for (int i = 0; i < 4; ++i)
      #pragma unroll
      for (int j = 0; j < 8; ++j)
        accE[i][j] = __builtin_amdgcn_mfma_f32_16x16x32_bf16(aE[cur][i], bqE[j], accE[i][j], 0, 0, 0);
    __builtin_amdgcn_s_setprio(0);
    bf16x8 bqO[8];
    #pragma unroll
    for (int j = 0; j < 8; ++j){
      int C  = C0[j] + s * 4;
      int ad = (C ^ ((C >> 4) & 15)) << 4;
      bqO[j] = *(const bf16x8*)(LDS + EB2 + ad);
    }
    __builtin_amdgcn_s_setprio(1);
    #pragma unroll
    for (int i = 0; i < 4; ++i)
      #pragma unroll
      for (int j = 0; j < 8; ++j)
        accO[i][j] = __builtin_amdgcn_mfma_f32_16x16x32_bf16(aO[cur][i], bqO[j], accO[i][j], 0, 0, 0);
    __builtin_amdgcn_s_setprio(0);
  }

  // ---- transpose fill: u32 tile [256 tl][64 slots], f = slot ^ ((tl&7)<<2) ----
  __syncthreads();   // all K-loop LDS reads done; safe to overwrite audio planes
  #pragma unroll
  for (int i = 0; i < 4; ++i){
    int cp1 = wm * 16 + i * 4 + h;          // 0..31
    int mp  = 63 - cp1;                     // 32..63
    #pragma unroll
    for (int j = 0; j < 8; ++j){
      int tl = wn * 128 + j * 16 + x;
      f32x4 E = accE[i][j], O = accO[i][j];
      float m1 = sqrtf((E[0]+O[0])*(E[0]+O[0]) + (E[1]+O[1])*(E[1]+O[1]));  // X[c0]
      float m2 = sqrtf((E[2]+O[2])*(E[2]+O[2]) + (E[3]+O[3])*(E[3]+O[3]));  // X[c0+1]
      float m3 = sqrtf((E[0]-O[0])*(E[0]-O[0]) + (E[1]-O[1])*(E[1]-O[1]));  // X[512-c0]
      float m4 = sqrtf((E[2]-O[2])*(E[2]-O[2]) + (E[3]-O[3])*(E[3]-O[3]));  // X[511-c0]
      unsigned p1 = (unsigned)f2bf(m1) | ((unsigned)f2bf(m2) << 16);
      unsigned p2 = (unsigned)f2bf(m4) | ((unsigned)f2bf(m3) << 16);
      int xs = (tl & 7) << 2;
      *(unsigned*)(LDS + tl * 256 + ((cp1 ^ xs) << 2)) = p1;
      *(unsigned*)(LDS + tl * 256 + ((mp  ^ xs) << 2)) = p2;
    }
  }
  __syncthreads();

  // ---- coalesced readout: 16 passes, 16B/thread ----
  {
    const long rowbase = (long)(nt2 * 256) * CPAD;
    int slot8 = tid & 15, rr = tid >> 4;
    int cb0 = (slot8 < 8) ? (64 * g + slot8 * 8) : (392 - 64 * g + slot8 * 8);
    #pragma unroll
    for (int pass = 0; pass < 16; ++pass){
      int tl = pass * 16 + rr;
      int f4 = (slot8 * 4) ^ ((tl & 7) << 2);
      i32x4 vv = *(const i32x4*)(LDS + tl * 256 + f4 * 4);
      *(i32x4*)((char*)magT + (rowbase + (long)tl * CPAD + cb0) * 2) = vv;
    }
  }
}

// ---------- k_mel: [80][576] x [576][t] + log(clip) -> out [32][80][1024] f32 ----------
__launch_bounds__(256)
__global__ void k_mel(const unsigned short* __restrict__ wb,
                      const unsigned short* __restrict__ magT,
                      float* __restrict__ out){
  __shared__ unsigned short Ws[80 * 32];
  __shared__ unsigned short Ms[128 * 32];
  int tid  = threadIdx.x, lane = tid & 63, wid = tid >> 6;
  int bx   = blockIdx.x;
  int bt   = bx & 7, b = bx >> 3;
  int t0   = bt * 128;
  f32x4 acc[5][2] = {};
  const char* Mb = (const char*)(magT + ((long)b * 1024 + t0) * CPAD);
  const char* Wb = (const char*)wb;

  for (int kt = 0; kt < 18; ++kt){
    int k0b = kt * 64;
    {
      int o = tid * 16;
      gload_lds16(Wb + (o >> 6) * 1152 + k0b + (o & 63), (char*)Ws + wid * 1024);
      if (wid == 0){
        int o2 = 4096 + lane * 16;
        gload_lds16(Wb + (o2 >> 6) * 1152 + k0b + (o2 & 63), (char*)Ws + 4096);
      }
    }
    #pragma unroll
    for (int q = 0; q < 2; ++q){
      int o = (q * 256 + tid) * 16;
      gload_lds16(Mb + (long)(o >> 6) * 1152 + k0b + (o & 63), (char*)Ms + q * 4096 + wid * 1024);
    }
    __syncthreads();
    bf16x8 af[5], bfr[2];
    int kb = (lane >> 4) << 4;
    #pragma unroll
    for (int i = 0; i < 5; ++i)
      af[i] = *(const bf16x8*)((const char*)Ws + (i*16 + (lane & 15)) * 64 + kb);
    #pragma unroll
    for (int j = 0; j < 2; ++j)
      bfr[j] = *(const bf16x8*)((const char*)Ms + (wid*32 + j*16 + (lane & 15)) * 64 + kb);
    #pragma unroll
    for (int i = 0; i < 5; ++i)
      #pragma unroll
      for (int j = 0; j < 2; ++j)
        acc[i][j] = __builtin_amdgcn_mfma_f32_16x16x32_bf16(af[i], bfr[j], acc[i][j], 0, 0, 0);
    __syncthreads();
  }
  #pragma unroll
  for (int i = 0; i < 5; ++i)
    #pragma unroll
    for (int j = 0; j < 2; ++j){
      int m = i*16 + ((lane >> 4) << 2);
      int t = t0 + wid*32 + j*16 + (lane & 15);
      #pragma unroll
      for (int r = 0; r < 4; ++r){
        float v = acc[i][j][r];
        out[((long)b * NMELS + (m + r)) * 1024 + t] = logf(fmaxf(v, 1e-5f));
      }
    }
}

__global__ void k_sentinel(float* out, int n){
  int i = blockIdx.x * 256 + threadIdx.x;
  if (i < n) out[i] = 12345.0f;
}

extern "C" void kernel_launch(void* const* d_in, const int* in_sizes, int n_in,
                              void* d_out, int out_size, void* d_ws, size_t ws_size,
                              hipStream_t stream){
  const float* audio = (const float*)d_in[0];
  const float* basis = (const float*)d_in[1];
  const float* melw  = (const float*)d_in[2];
  float* out = (float*)d_out;

  size_t off_bi  = 0;                                            // bi2f: 1 MB
  size_t off_wb  = (size_t)1024 * 1024;
  size_t off_mag = off_wb + (size_t)NMELS * CPAD * 2;
  size_t total   = off_mag + (size_t)32 * 1024 * CPAD * 2;       // ~38.9 MB

  if (ws_size < total){
    k_sentinel<<<(out_size + 255) / 256, 256, 0, stream>>>(out, out_size);
    return;
  }
  char* ws = (char*)d_ws;
  unsigned short* bi2f = (unsigned short*)(ws + off_bi);
  unsigned short* wb   = (unsigned short*)(ws + off_wb);
  unsigned short* magT = (unsigned short*)(ws + off_mag);

  k_extra <<<16384, 256, 0, stream>>>(audio, basis, magT);
  k_basis4<<<  256, 256, 0, stream>>>(basis, bi2f);
  k_w     <<<  180, 256, 0, stream>>>(melw, wb);
  k_stft  <<<  512, 256, 0, stream>>>(bi2f, audio, magT);
  k_mel   <<<  256, 256, 0, stream>>>(wb, magT, out);
}

// Round 13
// 77.562 us; speedup vs baseline: 1.3877x; 1.3877x over previous
//
#include <hip/hip_runtime.h>
#include <hip/hip_bf16.h>

typedef short bf16x8 __attribute__((ext_vector_type(8)));
typedef float f32x4  __attribute__((ext_vector_type(4)));
typedef int   i32x4  __attribute__((ext_vector_type(4)));

#define T_AUDIO 262144
#define PADL 384
#define CUTOFF 513
#define CPAD 576       // layout: p=c for c<=256, hole 257..263, p=c+7 for c>=257, tail 520..575 zero
#define NMELS 80
#define SEGLEN 33536   // 127*256 + 1024 samples per 128-frame tile
#define EBYTES 33536   // bytes per parity plane in LDS (2096 chunks)
#define PCH 16448      // chunks per global plane (per b, per parity)
#define PBYTES (PCH*16)

__device__ __forceinline__ unsigned short f2bf(float f){
  union { float f; unsigned u; } v; v.f = f;
  return (unsigned short)((v.u + 0x7FFFu + ((v.u >> 16) & 1u)) >> 16);
}
__device__ __forceinline__ float bf2f(unsigned short u){
  union { unsigned u; float f; } v; v.u = (unsigned)u << 16; return v.f;
}

__device__ __forceinline__ void gload_lds16(const void* g, void* l){
  __builtin_amdgcn_global_load_lds(
      (const __attribute__((address_space(1))) unsigned int*)g,
      (__attribute__((address_space(3))) unsigned int*)l, 16, 0, 0);
}

// ---------- k_audio: reflect-padded bf16 E/O planes, natural layout ----------
// plane element i (origin i=-192 at chunk 0): E[i]=bf16(audio[2i]), O[i]=bf16(audio[2i+1])
__global__ void k_audio(const float* __restrict__ audio, unsigned short* __restrict__ planes){
  int bx = blockIdx.x;              // 2080 blocks = 32 b x 65
  int b  = bx / 65;
  int ci = (bx % 65) * 256 + threadIdx.x;
  if (ci >= PCH) return;
  const float* ap = audio + (long)b * T_AUDIO;
  int s0 = 16 * ci - 384;
  float v[16];
  if (s0 >= 0 && s0 + 15 < T_AUDIO){
    #pragma unroll
    for (int q = 0; q < 4; ++q){
      f32x4 a = *(const f32x4*)(ap + s0 + q * 4);
      v[q*4]=a[0]; v[q*4+1]=a[1]; v[q*4+2]=a[2]; v[q*4+3]=a[3];
    }
  } else {
    #pragma unroll
    for (int e = 0; e < 16; ++e){
      int s = s0 + e;
      if (s < 0) s = -s;
      if (s >= T_AUDIO) s = 2*(T_AUDIO-1) - s;
      v[e] = ap[s];
    }
  }
  bf16x8 ev, ov;
  #pragma unroll
  for (int e = 0; e < 8; ++e){
    ev[e] = (short)f2bf(v[2*e]);
    ov[e] = (short)f2bf(v[2*e+1]);
  }
  unsigned short* pE = planes + (long)b * 2 * (PCH * 8);
  *(bf16x8*)(pE + (long)ci * 8)            = ev;
  *(bf16x8*)(pE + PCH * 8 + (long)ci * 8)  = ov;
}

// ---------- k_basis4: frag-major A  bi2f[(((g*2+p)*16+s)*8+f)*64+l] 16B chunks ----------
__global__ void k_basis4(const float* __restrict__ basis, unsigned short* __restrict__ bi2f){
  int CI = blockIdx.x * 256 + threadIdx.x;     // 65536 chunks
  int l  = CI & 63;
  int f  = (CI >> 6) & 7;
  int s  = (CI >> 9) & 15;
  int p  = (CI >> 13) & 1;
  int g  = CI >> 14;
  int R  = g * 128 + (f >> 2) * 64 + (f & 3) * 16 + (l & 15);
  int srcr = (R >> 1) + 513 * (R & 1);
  const float* sp = basis + srcr * 1024 + 2 * (s * 32 + (l >> 4) * 8) + p;
  bf16x8 o;
  #pragma unroll
  for (int e = 0; e < 8; ++e) o[e] = (short)f2bf(sp[2*e]);
  *(bf16x8*)(bi2f + (long)CI * 8) = o;
}

// ---------- k_w: mel weights [80][576] bf16 (mirror-shifted +7) + basisEO extract ----------
__global__ void k_w(const float* __restrict__ w, const float* __restrict__ basis,
                    unsigned short* __restrict__ wb, float* __restrict__ beo){
  int gid = blockIdx.x * 256 + threadIdx.x;    // 184 blocks = 47104 = 46080 + 1024
  if (gid < NMELS * CPAD){
    int m = gid / CPAD, p = gid % CPAD;
    float v = 0.f;
    if (p <= 256) v = w[m * CUTOFF + p];
    else if (p >= 264 && p <= 519) v = w[m * CUTOFF + (p - 7)];
    wb[gid] = f2bf(v);
  } else {
    int g2 = gid - NMELS * CPAD;               // 0..1023
    int par = g2 >> 9, m = g2 & 511;
    beo[g2] = par ? basis[769 * 1024 + 2*m + 1] : basis[256 * 1024 + 2*m];
  }
}

// ---------- k_extra: bin-256 from planes + zero pad cols ----------
__global__ void k_extra(const unsigned short* __restrict__ planes,
                        const float* __restrict__ beo,
                        unsigned short* __restrict__ magT){
  int tid = threadIdx.x, l = tid & 63, w = tid >> 6;
  long fr = (long)blockIdx.x * 4 + w;          // 0..32767
  int b = (int)(fr >> 10), t = (int)(fr & 1023);
  const unsigned short* pE = planes + (long)b * 2 * (PCH * 8);
  const unsigned short* pO = pE + PCH * 8;
  int idx = t * 128 + l * 8;                   // plane element index (origin-shifted)
  bf16x8 ev = *(const bf16x8*)(pE + idx);
  bf16x8 ov = *(const bf16x8*)(pO + idx);
  f32x4 be0 = *(const f32x4*)(beo + l*8);
  f32x4 be1 = *(const f32x4*)(beo + l*8 + 4);
  f32x4 bo0 = *(const f32x4*)(beo + 512 + l*8);
  f32x4 bo1 = *(const f32x4*)(beo + 512 + l*8 + 4);
  float re = bf2f(ev[0])*be0[0] + bf2f(ev[1])*be0[1] + bf2f(ev[2])*be0[2] + bf2f(ev[3])*be0[3]
           + bf2f(ev[4])*be1[0] + bf2f(ev[5])*be1[1] + bf2f(ev[6])*be1[2] + bf2f(ev[7])*be1[3];
  float im = bf2f(ov[0])*bo0[0] + bf2f(ov[1])*bo0[1] + bf2f(ov[2])*bo0[2] + bf2f(ov[3])*bo0[3]
           + bf2f(ov[4])*bo1[0] + bf2f(ov[5])*bo1[1] + bf2f(ov[6])*bo1[2] + bf2f(ov[7])*bo1[3];
  #pragma unroll
  for (int m = 1; m < 64; m <<= 1){
    re += __shfl_xor(re, m, 64);
    im += __shfl_xor(im, m, 64);
  }
  long tg = fr * CPAD;
  if (l == 0) magT[tg + 256] = f2bf(sqrtf(re*re + im*im));
  if (l < 63){
    int p = (l < 7) ? (257 + l) : (513 + l);   // hole 257..263, tail 520..575
    magT[tg + p] = 0;
  }
}

// ---------- k_stft: barrier-free E/O GEMM, plane staging via gload_lds, pipelined B ----------
__launch_bounds__(256, 2)
__global__ void k_stft(const unsigned short* __restrict__ bi2f,
                       const unsigned short* __restrict__ planes,
                       unsigned short* __restrict__ magT){
  __shared__ __align__(16) char LDS[2 * EBYTES];   // evens | odds ; reused for transpose
  const int tid = threadIdx.x;
  const int l   = tid & 63, w = tid >> 6;
  const int wm  = w >> 1, wn = w & 1;
  const int x   = l & 15, h = l >> 4;

  int bx = blockIdx.x;
  int sw = ((bx & 7) << 7) | (bx >> 3);   // XCD swizzle (1024 % 8 == 0, bijective)
  const int g  = sw & 3;
  const int nt = sw >> 2;                 // frames [nt*128, +128)

  // ---- stage planes -> LDS: linear dest, sigma-preswizzled source (rule #21) ----
  {
    const char* pb = (const char*)planes + (long)(nt >> 3) * 2 * PBYTES;
    const int k7o = (nt & 7) * 2048;      // tile chunk offset (mult of 256 -> sigma invariant)
    #pragma unroll
    for (int it = 0; it < 9; ++it){
      int o = it * 256 + tid;
      if (o < 2096){
        long so = (long)((o ^ ((o >> 4) & 15)) + k7o) * 16;
        gload_lds16(pb + so,          LDS + o * 16);
        gload_lds16(pb + PBYTES + so, LDS + EBYTES + o * 16);
      }
    }
  }
  asm volatile("s_waitcnt vmcnt(0)" ::: "memory");
  __syncthreads();

  // ---- A frag-major bases (L2-resident) ----
  const char* AgE = (const char*)bi2f + (long)(g * 256 + wm * 4) * 1024 + l * 16;
  const char* AgO = AgE + 131072;

  int C0[4];
  #pragma unroll
  for (int j = 0; j < 4; ++j) C0[j] = (wn * 64 + j * 16 + x) * 16 + h;

  f32x4 accE[4][4] = {}, accO[4][4] = {};
  bf16x8 aE[2][4], aO[2][4], bqE[4], bqO[4];
  #pragma unroll
  for (int i = 0; i < 4; ++i){
    aE[0][i] = *(const bf16x8*)(AgE + i * 1024);
    aO[0][i] = *(const bf16x8*)(AgO + i * 1024);
  }
  #pragma unroll
  for (int j = 0; j < 4; ++j){
    int C = C0[j]; int ad = (C ^ ((C >> 4) & 15)) << 4;
    bqE[j] = *(const bf16x8*)(LDS + ad);
    bqO[j] = *(const bf16x8*)(LDS + EBYTES + ad);
  }

  #pragma unroll
  for (int s = 0; s < 16; ++s){
    const int cur = s & 1, nxt = cur ^ 1;
    if (s < 15){
      #pragma unroll
      for (int i = 0; i < 4; ++i){
        aE[nxt][i] = *(const bf16x8*)(AgE + (s + 1) * 8192 + i * 1024);
        aO[nxt][i] = *(const bf16x8*)(AgO + (s + 1) * 8192 + i * 1024);
      }
    }
    __builtin_amdgcn_s_setprio(1);
    #pragma unroll
    for (int i = 0; i < 4; ++i)
      #pragma unroll
      for (int j = 0; j < 4; ++j)
        accE[i][j] = __builtin_amdgcn_mfma_f32_16x16x32_bf16(aE[cur][i], bqE[j], accE[i][j], 0, 0, 0);
    __builtin_amdgcn_s_setprio(0);
    if (s < 15){                         // read next-step E frags; hidden under O cluster
      #pragma unroll
      for (int j = 0; j < 4; ++j){
        int C = C0[j] + (s + 1) * 4; int ad = (C ^ ((C >> 4) & 15)) << 4;
        bqE[j] = *(const bf16x8*)(LDS + ad);
      }
    }
    __builtin_amdgcn_s_setprio(1);
    #pragma unroll
    for (int i = 0; i < 4; ++i)
      #pragma unroll
      for (int j = 0; j < 4; ++j)
        accO[i][j] = __builtin_amdgcn_mfma_f32_16x16x32_bf16(aO[cur][i], bqO[j], accO[i][j], 0, 0, 0);
    __builtin_amdgcn_s_setprio(0);
    if (s < 15){                         // read next-step O frags; hidden under next E cluster
      #pragma unroll
      for (int j = 0; j < 4; ++j){
        int C = C0[j] + (s + 1) * 4; int ad = (C ^ ((C >> 4) & 15)) << 4;
        bqO[j] = *(const bf16x8*)(LDS + EBYTES + ad);
      }
    }
  }

  // ---- transpose fill: u32 tile [128 tl][64 slots], f = slot ^ ((tl&7)<<2) ----
  __syncthreads();   // all K-loop LDS reads done; safe to overwrite audio planes
  #pragma unroll
  for (int i = 0; i < 4; ++i){
    int cp1 = wm * 16 + i * 4 + h;          // 0..31
    int mp  = 63 - cp1;                     // 32..63
    #pragma unroll
    for (int j = 0; j < 4; ++j){
      int tl = wn * 64 + j * 16 + x;
      f32x4 E = accE[i][j], O = accO[i][j];
      float m1 = sqrtf((E[0]+O[0])*(E[0]+O[0]) + (E[1]+O[1])*(E[1]+O[1]));  // X[c0]
      float m2 = sqrtf((E[2]+O[2])*(E[2]+O[2]) + (E[3]+O[3])*(E[3]+O[3]));  // X[c0+1]
      float m3 = sqrtf((E[0]-O[0])*(E[0]-O[0]) + (E[1]-O[1])*(E[1]-O[1]));  // X[512-c0]
      float m4 = sqrtf((E[2]-O[2])*(E[2]-O[2]) + (E[3]-O[3])*(E[3]-O[3]));  // X[511-c0]
      unsigned p1 = (unsigned)f2bf(m1) | ((unsigned)f2bf(m2) << 16);
      unsigned p2 = (unsigned)f2bf(m4) | ((unsigned)f2bf(m3) << 16);
      int xs = (tl & 7) << 2;
      *(unsigned*)(LDS + tl * 256 + ((cp1 ^ xs) << 2)) = p1;
      *(unsigned*)(LDS + tl * 256 + ((mp  ^ xs) << 2)) = p2;
    }
  }
  __syncthreads();

  // ---- coalesced readout: 8 passes, 16B/thread ----
  {
    const long rowbase = (long)(nt * 128) * CPAD;
    int slot8 = tid & 15, rr = tid >> 4;
    int cb0 = (slot8 < 8) ? (64 * g + slot8 * 8) : (392 - 64 * g + slot8 * 8);
    #pragma unroll
    for (int pass = 0; pass < 8; ++pass){
      int tl = pass * 16 + rr;
      int f4 = (slot8 * 4) ^ ((tl & 7) << 2);
      i32x4 vv = *(const i32x4*)(LDS + tl * 256 + f4 * 4);
      *(i32x4*)((char*)magT + (rowbase + (long)tl * CPAD + cb0) * 2) = vv;
    }
  }
}

// ---------- k_mel: [80][576] x [576][t] + log(clip) -> out [32][80][1024] f32 ----------
__launch_bounds__(256)
__global__ void k_mel(const unsigned short* __restrict__ wb,
                      const unsigned short* __restrict__ magT,
                      float* __restrict__ out){
  __shared__ unsigned short Ws[80 * 32];
  __shared__ unsigned short Ms[128 * 32];
  int tid  = threadIdx.x, lane = tid & 63, wid = tid >> 6;
  int bx   = blockIdx.x;
  int bt   = bx & 7, b = bx >> 3;
  int t0   = bt * 128;
  f32x4 acc[5][2] = {};
  const char* Mb = (const char*)(magT + ((long)b * 1024 + t0) * CPAD);
  const char* Wb = (const char*)wb;

  for (int kt = 0; kt < 18; ++kt){
    int k0b = kt * 64;
    {
      int o = tid * 16;
      gload_lds16(Wb + (o >> 6) * 1152 + k0b + (o & 63), (char*)Ws + wid * 1024);
      if (wid == 0){
        int o2 = 4096 + lane * 16;
        gload_lds16(Wb + (o2 >> 6) * 1152 + k0b + (o2 & 63), (char*)Ws + 4096);
      }
    }
    #pragma unroll
    for (int q = 0; q < 2; ++q){
      int o = (q * 256 + tid) * 16;
      gload_lds16(Mb + (long)(o >> 6) * 1152 + k0b + (o & 63), (char*)Ms + q * 4096 + wid * 1024);
    }
    __syncthreads();
    bf16x8 af[5], bfr[2];
    int kb = (lane >> 4) << 4;
    #pragma unroll
    for (int i = 0; i < 5; ++i)
      af[i] = *(const bf16x8*)((const char*)Ws + (i*16 + (lane & 15)) * 64 + kb);
    #pragma unroll
    for (int j = 0; j < 2; ++j)
      bfr[j] = *(const bf16x8*)((const char*)Ms + (wid*32 + j*16 + (lane & 15)) * 64 + kb);
    #pragma unroll
    for (int i = 0; i < 5; ++i)
      #pragma unroll
      for (int j = 0; j < 2; ++j)
        acc[i][j] = __builtin_amdgcn_mfma_f32_16x16x32_bf16(af[i], bfr[j], acc[i][j], 0, 0, 0);
    __syncthreads();
  }
  #pragma unroll
  for (int i = 0; i < 5; ++i)
    #pragma unroll
    for (int j = 0; j < 2; ++j){
      int m = i*16 + ((lane >> 4) << 2);
      int t = t0 + wid*32 + j*16 + (lane & 15);
      #pragma unroll
      for (int r = 0; r < 4; ++r){
        float v = acc[i][j][r];
        out[((long)b * NMELS + (m + r)) * 1024 + t] = logf(fmaxf(v, 1e-5f));
      }
    }
}

__global__ void k_sentinel(float* out, int n){
  int i = blockIdx.x * 256 + threadIdx.x;
  if (i < n) out[i] = 12345.0f;
}

extern "C" void kernel_launch(void* const* d_in, const int* in_sizes, int n_in,
                              void* d_out, int out_size, void* d_ws, size_t ws_size,
                              hipStream_t stream){
  const float* audio = (const float*)d_in[0];
  const float* basis = (const float*)d_in[1];
  const float* melw  = (const float*)d_in[2];
  float* out = (float*)d_out;

  size_t off_bi  = 0;                                            // bi2f: 1 MB
  size_t off_wb  = (size_t)1024 * 1024;
  size_t off_beo = off_wb + (size_t)NMELS * CPAD * 2;            // 4 KB f32 basisEO
  size_t off_mag = off_beo + 1024 * 4;
  size_t off_pl  = off_mag + (size_t)32 * 1024 * CPAD * 2;
  size_t total   = off_pl + (size_t)32 * 2 * PBYTES;             // ~55.7 MB

  if (ws_size < total){
    k_sentinel<<<(out_size + 255) / 256, 256, 0, stream>>>(out, out_size);
    return;
  }
  char* ws = (char*)d_ws;
  unsigned short* bi2f   = (unsigned short*)(ws + off_bi);
  unsigned short* wb     = (unsigned short*)(ws + off_wb);
  float*          beo    = (float*)(ws + off_beo);
  unsigned short* magT   = (unsigned short*)(ws + off_mag);
  unsigned short* planes = (unsigned short*)(ws + off_pl);

  k_audio <<< 2080, 256, 0, stream>>>(audio, planes);
  k_basis4<<<  256, 256, 0, stream>>>(basis, bi2f);
  k_w     <<<  184, 256, 0, stream>>>(melw, basis, wb, beo);
  k_extra <<< 8192, 256, 0, stream>>>(planes, beo, magT);
  k_stft  <<< 1024, 256, 0, stream>>>(bi2f, planes, magT);
  k_mel   <<<  256, 256, 0, stream>>>(wb, magT, out);
}